// Round 16
// baseline (95.277 us; speedup 1.0000x reference)
//
#include <hip/hip_runtime.h>

typedef float v4f __attribute__((ext_vector_type(4)));
typedef short v8s __attribute__((ext_vector_type(8)));
typedef v8s v8s_a __attribute__((may_alias));

#define PBLOCKS 128   // p-path blocks (8 pairs per block, 1024 p-pairs)
#define NEG 0.2f

// Truncation split for ACTIVATIONS/adjacency (validated): hi = bit-truncated
// bf16, lo = trunc(v - hi); v = hi + lo + err, |err| <= 2^-17 |v|.
static __device__ __forceinline__ void split8(const float* e, v8s& hi, v8s& lo) {
  union U { v8s s; unsigned u[4]; } H, L;
#pragma unroll
  for (int j = 0; j < 4; ++j) {
    union { float f; unsigned u; } e0, e1, h0, h1, l0, l1;
    e0.f = e[2 * j]; e1.f = e[2 * j + 1];
    H.u[j] = __builtin_amdgcn_perm(e1.u, e0.u, 0x07060302u);
    h0.u = e0.u & 0xFFFF0000u; h1.u = e1.u & 0xFFFF0000u;
    l0.f = e0.f - h0.f; l1.f = e1.f - h1.f;
    L.u[j] = __builtin_amdgcn_perm(l1.u, l0.u, 0x07060302u);
  }
  hi = H.s; lo = L.s;
}

// Single-plane RNE pack for WEIGHTS (validated round 13).
static __device__ __forceinline__ v8s rne8(const float* e) {
  union U { v8s s; unsigned u[4]; } H;
#pragma unroll
  for (int j = 0; j < 4; ++j) {
    union { float f; unsigned u; } e0, e1;
    e0.f = e[2 * j]; e1.f = e[2 * j + 1];
    const unsigned r0 = e0.u + 0x7FFFu + ((e0.u >> 16) & 1u);
    const unsigned r1 = e1.u + 0x7FFFu + ((e1.u >> 16) & 1u);
    H.u[j] = __builtin_amdgcn_perm(r1, r0, 0x07060302u);
  }
  return H.s;
}

// ---- prep: pack both weight sets' MFMA fragments into d_ws ----
// Layout: ws[set][frag 0..27][lane 0..63][8 bf16]; set 0 = p, 1 = n.
// frags 0..7 = W2, 8..15 = Wm, 16..23 = Ws (B-layout: elem j at
// k = kt*32 + 8g + j, col (nt*16 + n)); 24..27 = W1stk^T (A-layout,
// quarters g>=2 zero).
__global__ __launch_bounds__(256, 1)
void prep_frags(const float* __restrict__ W1p, const float* __restrict__ W2p,
                const float* __restrict__ WMp, const float* __restrict__ WSp,
                const float* __restrict__ W1n, const float* __restrict__ W2n,
                const float* __restrict__ WMn, const float* __restrict__ WSn,
                short* __restrict__ ws)
{
  const bool isp = (blockIdx.x == 0);
  const float* W1 = isp ? W1p : W1n;
  const float* W2 = isp ? W2p : W2n;
  const float* WM = isp ? WMp : WMn;
  const float* WS = isp ? WSp : WSn;
  short* dst = ws + blockIdx.x * 28 * 512;

  const int l = threadIdx.x & 63;
  const int w = threadIdx.x >> 6;
  const int n = l & 15;
  const int g = l >> 4;

  for (int f = w; f < 28; f += 4) {
    float v[8];
    if (f < 24) {
      const float* M = (f < 8) ? W2 : ((f < 16) ? WM : WS);
      const int r = f & 7;
      const int kt = r >> 2;
      const int cn = (r & 3) * 16 + n;
#pragma unroll
      for (int j = 0; j < 8; ++j)
        v[j] = M[(kt * 32 + g * 8 + j) * 64 + cn];
    } else {
      const int ft = f - 24;
#pragma unroll
      for (int j = 0; j < 8; ++j)
        v[j] = (g < 2) ? W1[j * 64 + ft * 16 + n] : 0.0f;
    }
    *(v8s_a*)&dst[f * 512 + l * 8] = rne8(v);
  }
}

// All-register MFMA chain, compensated activations x single-bf16 weights.
// Round 16: TWO pairs per wave, fully unrolled (two independent straight-line
// chains -> ILP; TLP is pinned ~3.2 waves/SIMD per r12-r15 evidence, so extra
// per-wave parallelism is the remaining concurrency lever). No LDS, no
// barrier; weights pre-packed by prep_frags (L1-resident). Chain (r13):
//   x1^T = W1stk^T @ Ablk^T   (C lane = pair-row)
//   t    = x1 @ W2            (C lane = feat)     A-frag via CtoA(x1^T)
//   x2^T = t^T @ Ablk^T       (C lane = pair-row)
//   m,s  = x2 @ {Wm,Ws}       (C lane = feat)     A-frag via CtoA(x2^T)
// A/B frag: lane l elem j <-> k = 8*(l>>4)+j (positional, cancels);
// C/D [m89]: row = 4*(l>>4)+reg, col = l&15.
__global__ __launch_bounds__(256, 1)
void enc_reg(const float* __restrict__ adj, const float* __restrict__ noise,
             const short* __restrict__ ws,
             const float* __restrict__ b1p, const float* __restrict__ b2p,
             const float* __restrict__ bmp, const float* __restrict__ gmp,
             const float* __restrict__ betamp,
             const float* __restrict__ bsp, const float* __restrict__ gsp,
             const float* __restrict__ betasp,
             const float* __restrict__ b1n, const float* __restrict__ b2n,
             const float* __restrict__ bmn, const float* __restrict__ gmn,
             const float* __restrict__ betamn,
             const float* __restrict__ bsn, const float* __restrict__ gsn,
             const float* __restrict__ betasn,
             float* __restrict__ out)
{
  const int tid = threadIdx.x;
  const int l = tid & 63;
  const int w = tid >> 6;
  const int n = l & 15;   // preserved axis (pair-row or feat-col)
  const int g = l >> 4;   // lane quarter

  const bool isp = (blockIdx.x < PBLOCKS);
  const int bip = isp ? (int)blockIdx.x : ((int)blockIdx.x - PBLOCKS);

  const float* B1 = isp ? b1p : b1n;   const float* B2 = isp ? b2p : b2n;
  const float* BM = isp ? bmp : bmn;   const float* GM = isp ? gmp : gmn;
  const float* BEM = isp ? betamp : betamn;
  const float* BS = isp ? bsp : bsn;   const float* GS = isp ? gsp : gsn;
  const float* BES = isp ? betasp : betasn;
  const short* fw = ws + (isp ? 0 : 1) * 28 * 512;

#pragma unroll
  for (int P = 0; P < 2; ++P) {
    // ---- pair instance indices (2 pairs per wave) ----
    const int gi = bip * 8 + w * 2 + P;
    int iA, iB;
    if (isp) {
      iA = gi * 64;            // b=2gi,   c=0
      iB = gi * 64 + 32;       // b=2gi+1, c=0
    } else {
      const unsigned n0 = 2u * (unsigned)gi;
      const unsigned n1 = n0 + 1u;
      const unsigned q0 = n0 / 31u;
      const unsigned q1 = n1 / 31u;
      iA = (int)(q0 * 32u + 1u + (n0 - q0 * 31u));
      iB = (int)(q1 * 32u + 1u + (n1 - q1 * 31u));
    }

    // ---- adjacency load + block-diagonal fragment ----
    v8s afh, afl;
    {
      const int instAdj = (n >> 3) ? iB : iA;
      const float4 a0 = *(const float4*)(adj + instAdj * 64 + (n & 7) * 8);
      const float4 a1 = *(const float4*)(adj + instAdj * 64 + (n & 7) * 8 + 4);
      float s = a0.x + a0.y + a0.z + a0.w + a1.x + a1.y + a1.z + a1.w;
      s = (s == 0.0f) ? 1.0f : s;
      const float rinv = (g == (n >> 3)) ? (1.0f / s) : 0.0f;  // kills off-diag
      float e[8];
      e[0] = a0.x * rinv; e[1] = a0.y * rinv; e[2] = a0.z * rinv; e[3] = a0.w * rinv;
      e[4] = a1.x * rinv; e[5] = a1.y * rinv; e[6] = a1.z * rinv; e[7] = a1.w * rinv;
      split8(e, afh, afl);
    }

    // ---- x1^T = W1stk^T @ Ablk^T + b1 (leaky) : C lane = pair-row ----
    v4f x1t[4];
#pragma unroll
    for (int ft = 0; ft < 4; ++ft) {
      const v8s w1h = *(const v8s_a*)&fw[(24 + ft) * 512 + l * 8];
      const float4 b14 = *(const float4*)&B1[ft * 16 + g * 4];
      v4f acc = { b14.x, b14.y, b14.z, b14.w };
      acc = __builtin_amdgcn_mfma_f32_16x16x32_bf16(w1h, afl, acc, 0, 0, 0);
      acc = __builtin_amdgcn_mfma_f32_16x16x32_bf16(w1h, afh, acc, 0, 0, 0);
#pragma unroll
      for (int q = 0; q < 4; ++q) acc[q] = fmaxf(acc[q], NEG * acc[q]);
      x1t[ft] = acc;
    }

    // ---- CtoA(x1t): (lane=pair-row, reg=feat) -> A-frag elems k=feat ----
    v8s xah[2], xal[2];
    {
      const int srcLo = ((g & 1) << 5) + n;
      const int srcHi = srcLo + 16;
#pragma unroll
      for (int kc = 0; kc < 2; ++kc) {
        float e[8];
#pragma unroll
        for (int j = 0; j < 4; ++j) {
          const float lo0 = __shfl(x1t[2 * kc][j], srcLo);
          const float lo1 = __shfl(x1t[2 * kc + 1][j], srcLo);
          const float hi0 = __shfl(x1t[2 * kc][j], srcHi);
          const float hi1 = __shfl(x1t[2 * kc + 1][j], srcHi);
          e[j]     = (g >> 1) ? lo1 : lo0;
          e[j + 4] = (g >> 1) ? hi1 : hi0;
        }
        split8(e, xah[kc], xal[kc]);
      }
    }

    // ---- t = x1 @ W2 : C lane = feat (no bias, no act) ----
    v4f tC[4];
#pragma unroll
    for (int nt = 0; nt < 4; ++nt) {
      v4f acc = { 0.0f, 0.0f, 0.0f, 0.0f };
#pragma unroll
      for (int kc = 0; kc < 2; ++kc) {
        const v8s bh = *(const v8s_a*)&fw[(kc * 4 + nt) * 512 + l * 8];
        acc = __builtin_amdgcn_mfma_f32_16x16x32_bf16(xal[kc], bh, acc, 0, 0, 0);
        acc = __builtin_amdgcn_mfma_f32_16x16x32_bf16(xah[kc], bh, acc, 0, 0, 0);
      }
      tC[nt] = acc;
    }

    // ---- x2^T = t^T @ Ablk^T + b2 (leaky) : C lane = pair-row ----
    v4f x2t[4];
    {
      const int sA = ((g & 1) << 5) + n;
      const int sB = sA + 16;
      const bool bval = (g < 2);
#pragma unroll
      for (int ft = 0; ft < 4; ++ft) {
        float e[8];
#pragma unroll
        for (int j = 0; j < 4; ++j) {
          const float v0 = __shfl(tC[ft][j], sA);
          const float v1 = __shfl(tC[ft][j], sB);
          e[j]     = bval ? v0 : 0.0f;
          e[j + 4] = bval ? v1 : 0.0f;
        }
        v8s th, tl;
        split8(e, th, tl);
        const float4 b24 = *(const float4*)&B2[ft * 16 + g * 4];
        v4f acc = { b24.x, b24.y, b24.z, b24.w };
        acc = __builtin_amdgcn_mfma_f32_16x16x32_bf16(tl, afh, acc, 0, 0, 0);
        acc = __builtin_amdgcn_mfma_f32_16x16x32_bf16(th, afl, acc, 0, 0, 0);
        acc = __builtin_amdgcn_mfma_f32_16x16x32_bf16(th, afh, acc, 0, 0, 0);
#pragma unroll
        for (int q = 0; q < 4; ++q) acc[q] = fmaxf(acc[q], NEG * acc[q]);
        x2t[ft] = acc;
      }
    }

    // ---- CtoA(x2t) -> x2 A-frags ----
    v8s yah[2], yal[2];
    {
      const int srcLo = ((g & 1) << 5) + n;
      const int srcHi = srcLo + 16;
#pragma unroll
      for (int kc = 0; kc < 2; ++kc) {
        float e[8];
#pragma unroll
        for (int j = 0; j < 4; ++j) {
          const float lo0 = __shfl(x2t[2 * kc][j], srcLo);
          const float lo1 = __shfl(x2t[2 * kc + 1][j], srcLo);
          const float hi0 = __shfl(x2t[2 * kc][j], srcHi);
          const float hi1 = __shfl(x2t[2 * kc + 1][j], srcHi);
          e[j]     = (g >> 1) ? lo1 : lo0;
          e[j + 4] = (g >> 1) ? hi1 : hi0;
        }
        split8(e, yah[kc], yal[kc]);
      }
    }

    // ---- m,s = x2 @ {Wm,Ws} + bias ; BN over 8 nodes ; reparam ; store ----
    const int obase0 = ((g >> 1) ? iB : iA) * 512 + (g & 1) * 256;
#pragma unroll
    for (int nt = 0; nt < 4; ++nt) {
      const int cn = nt * 16 + n;
      v4f mc;
      {
        const float bm0 = BM[cn];
        mc[0] = bm0; mc[1] = bm0; mc[2] = bm0; mc[3] = bm0;
        const v8s bh0 = *(const v8s_a*)&fw[(8 + nt) * 512 + l * 8];
        const v8s bh1 = *(const v8s_a*)&fw[(12 + nt) * 512 + l * 8];
        mc = __builtin_amdgcn_mfma_f32_16x16x32_bf16(yal[0], bh0, mc, 0, 0, 0);
        mc = __builtin_amdgcn_mfma_f32_16x16x32_bf16(yah[0], bh0, mc, 0, 0, 0);
        mc = __builtin_amdgcn_mfma_f32_16x16x32_bf16(yal[1], bh1, mc, 0, 0, 0);
        mc = __builtin_amdgcn_mfma_f32_16x16x32_bf16(yah[1], bh1, mc, 0, 0, 0);
      }
      v4f sc;
      {
        const float bs0 = BS[cn];
        sc[0] = bs0; sc[1] = bs0; sc[2] = bs0; sc[3] = bs0;
        const v8s bh0 = *(const v8s_a*)&fw[(16 + nt) * 512 + l * 8];
        const v8s bh1 = *(const v8s_a*)&fw[(20 + nt) * 512 + l * 8];
        sc = __builtin_amdgcn_mfma_f32_16x16x32_bf16(yal[0], bh0, sc, 0, 0, 0);
        sc = __builtin_amdgcn_mfma_f32_16x16x32_bf16(yah[0], bh0, sc, 0, 0, 0);
        sc = __builtin_amdgcn_mfma_f32_16x16x32_bf16(yal[1], bh1, sc, 0, 0, 0);
        sc = __builtin_amdgcn_mfma_f32_16x16x32_bf16(yah[1], bh1, sc, 0, 0, 0);
      }

      float smm = (mc[0] + mc[1]) + (mc[2] + mc[3]);
      smm += __shfl_xor(smm, 16);
      const float mum = smm * 0.125f;
      float sms = (sc[0] + sc[1]) + (sc[2] + sc[3]);
      sms += __shfl_xor(sms, 16);
      const float mus = sms * 0.125f;
      float vm = 0.0f, vs = 0.0f;
#pragma unroll
      for (int q = 0; q < 4; ++q) {
        const float dm = mc[q] - mum; vm = fmaf(dm, dm, vm);
        const float ds = sc[q] - mus; vs = fmaf(ds, ds, vs);
      }
      vm += __shfl_xor(vm, 16);
      vs += __shfl_xor(vs, 16);
      const float sclm = GM[cn] * rsqrtf(vm * 0.125f + 1e-5f);
      const float scls = GS[cn] * rsqrtf(vs * 0.125f + 1e-5f);
      const float bem = BEM[cn];
      const float bes = BES[cn];
      const int oc = obase0 + cn;
#pragma unroll
      for (int q = 0; q < 4; ++q) {
        const float nzq = noise[((g & 1) * 4 + q) * 64 + cn];
        const float lv = (sc[q] - mus) * scls + bes;
        const float ex = exp2f(0.72134752044448f * lv);  // exp(0.5*lv)
        out[oc + q * 64] = (mc[q] - mum) * sclm + bem + ex * nzq;
      }
    }
  }
}

extern "C" void kernel_launch(void* const* d_in, const int* in_sizes, int n_in,
                              void* d_out, int out_size, void* d_ws, size_t ws_size,
                              hipStream_t stream) {
  const float* adj   = (const float*)d_in[0];
  const float* noise = (const float*)d_in[1];
  const float* W1p = (const float*)d_in[2];  const float* b1p = (const float*)d_in[3];
  const float* W2p = (const float*)d_in[4];  const float* b2p = (const float*)d_in[5];
  const float* Wmp = (const float*)d_in[6];  const float* bmp = (const float*)d_in[7];
  const float* gmp = (const float*)d_in[8];  const float* betamp = (const float*)d_in[9];
  const float* Wsp = (const float*)d_in[10]; const float* bsp = (const float*)d_in[11];
  const float* gsp = (const float*)d_in[12]; const float* betasp = (const float*)d_in[13];
  const float* W1n = (const float*)d_in[14]; const float* b1n = (const float*)d_in[15];
  const float* W2n = (const float*)d_in[16]; const float* b2n = (const float*)d_in[17];
  const float* Wmn = (const float*)d_in[18]; const float* bmn = (const float*)d_in[19];
  const float* gmn = (const float*)d_in[20]; const float* betamn = (const float*)d_in[21];
  const float* Wsn = (const float*)d_in[22]; const float* bsn = (const float*)d_in[23];
  const float* gsn = (const float*)d_in[24]; const float* betasn = (const float*)d_in[25];

  short* ws = (short*)d_ws;  // needs 2*28*512*2 = 57344 bytes

  prep_frags<<<2, 256, 0, stream>>>(W1p, W2p, Wmp, Wsp, W1n, W2n, Wmn, Wsn, ws);

  // 128 p-blocks (1024 pairs) + 3968 n-blocks (31744 pairs) = 4096 blocks,
  // 8 pairs per block (4 waves x 2 pairs, fully unrolled).
  enc_reg<<<4096, 256, 0, stream>>>(
      adj, noise, ws,
      b1p, b2p, bmp, gmp, betamp, bsp, gsp, betasp,
      b1n, b2n, bmn, gmn, betamn, bsn, gsn, betasn,
      (float*)d_out);
}

// Round 17
// 87.145 us; speedup vs baseline: 1.0933x; 1.0933x over previous
//
#include <hip/hip_runtime.h>

typedef float v4f __attribute__((ext_vector_type(4)));
typedef short v8s __attribute__((ext_vector_type(8)));
typedef v8s v8s_a __attribute__((may_alias));

#define PBLOCKS 64    // p-path blocks (16 pairs per block, 1024 p-pairs)
#define NEG 0.2f

// Truncation split for ACTIVATIONS/adjacency (validated): hi = bit-truncated
// bf16, lo = trunc(v - hi); v = hi + lo + err, |err| <= 2^-17 |v|.
static __device__ __forceinline__ void split8(const float* e, v8s& hi, v8s& lo) {
  union U { v8s s; unsigned u[4]; } H, L;
#pragma unroll
  for (int j = 0; j < 4; ++j) {
    union { float f; unsigned u; } e0, e1, h0, h1, l0, l1;
    e0.f = e[2 * j]; e1.f = e[2 * j + 1];
    H.u[j] = __builtin_amdgcn_perm(e1.u, e0.u, 0x07060302u);
    h0.u = e0.u & 0xFFFF0000u; h1.u = e1.u & 0xFFFF0000u;
    l0.f = e0.f - h0.f; l1.f = e1.f - h1.f;
    L.u[j] = __builtin_amdgcn_perm(l1.u, l0.u, 0x07060302u);
  }
  hi = H.s; lo = L.s;
}

// Single-plane RNE pack for WEIGHTS (validated round 13).
static __device__ __forceinline__ v8s rne8(const float* e) {
  union U { v8s s; unsigned u[4]; } H;
#pragma unroll
  for (int j = 0; j < 4; ++j) {
    union { float f; unsigned u; } e0, e1;
    e0.f = e[2 * j]; e1.f = e[2 * j + 1];
    const unsigned r0 = e0.u + 0x7FFFu + ((e0.u >> 16) & 1u);
    const unsigned r1 = e1.u + 0x7FFFu + ((e1.u >> 16) & 1u);
    H.u[j] = __builtin_amdgcn_perm(r1, r0, 0x07060302u);
  }
  return H.s;
}

// ---- prep: pack both weight sets' MFMA fragments into d_ws ----
// Layout: ws[set][frag 0..27][lane 0..63][8 bf16]; set 0 = p, 1 = n.
// frags 0..7 = W2, 8..15 = Wm, 16..23 = Ws (B-layout: elem j at
// k = kt*32 + 8g + j, col (nt*16 + n)); 24..27 = W1stk^T (A-layout,
// quarters g>=2 zero).
__global__ __launch_bounds__(256, 1)
void prep_frags(const float* __restrict__ W1p, const float* __restrict__ W2p,
                const float* __restrict__ WMp, const float* __restrict__ WSp,
                const float* __restrict__ W1n, const float* __restrict__ W2n,
                const float* __restrict__ WMn, const float* __restrict__ WSn,
                short* __restrict__ ws)
{
  const bool isp = (blockIdx.x == 0);
  const float* W1 = isp ? W1p : W1n;
  const float* W2 = isp ? W2p : W2n;
  const float* WM = isp ? WMp : WMn;
  const float* WS = isp ? WSp : WSn;
  short* dst = ws + blockIdx.x * 28 * 512;

  const int l = threadIdx.x & 63;
  const int w = threadIdx.x >> 6;
  const int n = l & 15;
  const int g = l >> 4;

  for (int f = w; f < 28; f += 4) {
    float v[8];
    if (f < 24) {
      const float* M = (f < 8) ? W2 : ((f < 16) ? WM : WS);
      const int r = f & 7;
      const int kt = r >> 2;
      const int cn = (r & 3) * 16 + n;
#pragma unroll
      for (int j = 0; j < 8; ++j)
        v[j] = M[(kt * 32 + g * 8 + j) * 64 + cn];
    } else {
      const int ft = f - 24;
#pragma unroll
      for (int j = 0; j < 8; ++j)
        v[j] = (g < 2) ? W1[j * 64 + ft * 16 + n] : 0.0f;
    }
    *(v8s_a*)&dst[f * 512 + l * 8] = rne8(v);
  }
}

// All-register MFMA chain, compensated activations x single-bf16 weights.
// Round 17: same per-wave chain as r15 (validated, VGPR 56), but 1024-thread
// blocks (16 independent waves, no barrier) and grid 2048. Little's-law
// reading of r12-r15 says residency pins at ~3 blocks/CU because 8192
// short-lived 256-thread blocks arrive too slowly; 4x fewer, 4x fatter
// blocks fill 16 wave slots per allocation. Chain (r13):
//   x1^T = W1stk^T @ Ablk^T   (C lane = pair-row)
//   t    = x1 @ W2            (C lane = feat)     A-frag via CtoA(x1^T)
//   x2^T = t^T @ Ablk^T       (C lane = pair-row)
//   m,s  = x2 @ {Wm,Ws}       (C lane = feat)     A-frag via CtoA(x2^T)
// A/B frag: lane l elem j <-> k = 8*(l>>4)+j (positional, cancels);
// C/D [m89]: row = 4*(l>>4)+reg, col = l&15.
__global__ __launch_bounds__(1024, 1)
void enc_reg(const float* __restrict__ adj, const float* __restrict__ noise,
             const short* __restrict__ ws,
             const float* __restrict__ b1p, const float* __restrict__ b2p,
             const float* __restrict__ bmp, const float* __restrict__ gmp,
             const float* __restrict__ betamp,
             const float* __restrict__ bsp, const float* __restrict__ gsp,
             const float* __restrict__ betasp,
             const float* __restrict__ b1n, const float* __restrict__ b2n,
             const float* __restrict__ bmn, const float* __restrict__ gmn,
             const float* __restrict__ betamn,
             const float* __restrict__ bsn, const float* __restrict__ gsn,
             const float* __restrict__ betasn,
             float* __restrict__ out)
{
  const int tid = threadIdx.x;
  const int l = tid & 63;
  const int w = tid >> 6;   // 0..15
  const int n = l & 15;     // preserved axis (pair-row or feat-col)
  const int g = l >> 4;     // lane quarter

  const bool isp = (blockIdx.x < PBLOCKS);
  const int bip = isp ? (int)blockIdx.x : ((int)blockIdx.x - PBLOCKS);

  const float* B1 = isp ? b1p : b1n;   const float* B2 = isp ? b2p : b2n;
  const float* BM = isp ? bmp : bmn;   const float* GM = isp ? gmp : gmn;
  const float* BEM = isp ? betamp : betamn;
  const float* BS = isp ? bsp : bsn;   const float* GS = isp ? gsp : gsn;
  const float* BES = isp ? betasp : betasn;
  const short* fw = ws + (isp ? 0 : 1) * 28 * 512;

  // ---- pair instance indices (one pair per wave, 16 waves per block) ----
  const int gi = bip * 16 + w;
  int iA, iB;
  if (isp) {
    iA = gi * 64;            // b=2gi,   c=0
    iB = gi * 64 + 32;       // b=2gi+1, c=0
  } else {
    const unsigned n0 = 2u * (unsigned)gi;
    const unsigned n1 = n0 + 1u;
    const unsigned q0 = n0 / 31u;
    const unsigned q1 = n1 / 31u;
    iA = (int)(q0 * 32u + 1u + (n0 - q0 * 31u));
    iB = (int)(q1 * 32u + 1u + (n1 - q1 * 31u));
  }

  // ---- adjacency load + block-diagonal fragment ----
  v8s afh, afl;
  {
    const int instAdj = (n >> 3) ? iB : iA;
    const float4 a0 = *(const float4*)(adj + instAdj * 64 + (n & 7) * 8);
    const float4 a1 = *(const float4*)(adj + instAdj * 64 + (n & 7) * 8 + 4);
    float s = a0.x + a0.y + a0.z + a0.w + a1.x + a1.y + a1.z + a1.w;
    s = (s == 0.0f) ? 1.0f : s;
    const float rinv = (g == (n >> 3)) ? (1.0f / s) : 0.0f;  // 0 kills off-diag
    float e[8];
    e[0] = a0.x * rinv; e[1] = a0.y * rinv; e[2] = a0.z * rinv; e[3] = a0.w * rinv;
    e[4] = a1.x * rinv; e[5] = a1.y * rinv; e[6] = a1.z * rinv; e[7] = a1.w * rinv;
    split8(e, afh, afl);
  }

  // ---- x1^T = W1stk^T @ Ablk^T + b1 (leaky) : C lane = pair-row ----
  v4f x1t[4];
#pragma unroll
  for (int ft = 0; ft < 4; ++ft) {
    const v8s w1h = *(const v8s_a*)&fw[(24 + ft) * 512 + l * 8];
    const float4 b14 = *(const float4*)&B1[ft * 16 + g * 4];
    v4f acc = { b14.x, b14.y, b14.z, b14.w };
    acc = __builtin_amdgcn_mfma_f32_16x16x32_bf16(w1h, afl, acc, 0, 0, 0);
    acc = __builtin_amdgcn_mfma_f32_16x16x32_bf16(w1h, afh, acc, 0, 0, 0);
#pragma unroll
    for (int q = 0; q < 4; ++q) acc[q] = fmaxf(acc[q], NEG * acc[q]);
    x1t[ft] = acc;
  }

  // ---- CtoA(x1t): (lane=pair-row, reg=feat) -> A-frag elems k=feat ----
  v8s xah[2], xal[2];
  {
    const int srcLo = ((g & 1) << 5) + n;
    const int srcHi = srcLo + 16;
#pragma unroll
    for (int kc = 0; kc < 2; ++kc) {
      float e[8];
#pragma unroll
      for (int j = 0; j < 4; ++j) {
        const float lo0 = __shfl(x1t[2 * kc][j], srcLo);
        const float lo1 = __shfl(x1t[2 * kc + 1][j], srcLo);
        const float hi0 = __shfl(x1t[2 * kc][j], srcHi);
        const float hi1 = __shfl(x1t[2 * kc + 1][j], srcHi);
        e[j]     = (g >> 1) ? lo1 : lo0;
        e[j + 4] = (g >> 1) ? hi1 : hi0;
      }
      split8(e, xah[kc], xal[kc]);
    }
  }

  // ---- t = x1 @ W2 : C lane = feat (no bias, no act) ----
  v4f tC[4];
#pragma unroll
  for (int nt = 0; nt < 4; ++nt) {
    v4f acc = { 0.0f, 0.0f, 0.0f, 0.0f };
#pragma unroll
    for (int kc = 0; kc < 2; ++kc) {
      const v8s bh = *(const v8s_a*)&fw[(kc * 4 + nt) * 512 + l * 8];
      acc = __builtin_amdgcn_mfma_f32_16x16x32_bf16(xal[kc], bh, acc, 0, 0, 0);
      acc = __builtin_amdgcn_mfma_f32_16x16x32_bf16(xah[kc], bh, acc, 0, 0, 0);
    }
    tC[nt] = acc;
  }

  // ---- x2^T = t^T @ Ablk^T + b2 (leaky) : C lane = pair-row ----
  v4f x2t[4];
  {
    const int sA = ((g & 1) << 5) + n;
    const int sB = sA + 16;
    const bool bval = (g < 2);
#pragma unroll
    for (int ft = 0; ft < 4; ++ft) {
      float e[8];
#pragma unroll
      for (int j = 0; j < 4; ++j) {
        const float v0 = __shfl(tC[ft][j], sA);
        const float v1 = __shfl(tC[ft][j], sB);
        e[j]     = bval ? v0 : 0.0f;
        e[j + 4] = bval ? v1 : 0.0f;
      }
      v8s th, tl;
      split8(e, th, tl);
      const float4 b24 = *(const float4*)&B2[ft * 16 + g * 4];
      v4f acc = { b24.x, b24.y, b24.z, b24.w };
      acc = __builtin_amdgcn_mfma_f32_16x16x32_bf16(tl, afh, acc, 0, 0, 0);
      acc = __builtin_amdgcn_mfma_f32_16x16x32_bf16(th, afl, acc, 0, 0, 0);
      acc = __builtin_amdgcn_mfma_f32_16x16x32_bf16(th, afh, acc, 0, 0, 0);
#pragma unroll
      for (int q = 0; q < 4; ++q) acc[q] = fmaxf(acc[q], NEG * acc[q]);
      x2t[ft] = acc;
    }
  }

  // ---- CtoA(x2t) -> x2 A-frags ----
  v8s yah[2], yal[2];
  {
    const int srcLo = ((g & 1) << 5) + n;
    const int srcHi = srcLo + 16;
#pragma unroll
    for (int kc = 0; kc < 2; ++kc) {
      float e[8];
#pragma unroll
      for (int j = 0; j < 4; ++j) {
        const float lo0 = __shfl(x2t[2 * kc][j], srcLo);
        const float lo1 = __shfl(x2t[2 * kc + 1][j], srcLo);
        const float hi0 = __shfl(x2t[2 * kc][j], srcHi);
        const float hi1 = __shfl(x2t[2 * kc + 1][j], srcHi);
        e[j]     = (g >> 1) ? lo1 : lo0;
        e[j + 4] = (g >> 1) ? hi1 : hi0;
      }
      split8(e, yah[kc], yal[kc]);
    }
  }

  // ---- m,s = x2 @ {Wm,Ws} + bias ; BN over 8 nodes ; reparam ; store ----
  const int obase0 = ((g >> 1) ? iB : iA) * 512 + (g & 1) * 256;
#pragma unroll
  for (int nt = 0; nt < 4; ++nt) {
    const int cn = nt * 16 + n;
    v4f mc;
    {
      const float bm0 = BM[cn];
      mc[0] = bm0; mc[1] = bm0; mc[2] = bm0; mc[3] = bm0;
      const v8s bh0 = *(const v8s_a*)&fw[(8 + nt) * 512 + l * 8];
      const v8s bh1 = *(const v8s_a*)&fw[(12 + nt) * 512 + l * 8];
      mc = __builtin_amdgcn_mfma_f32_16x16x32_bf16(yal[0], bh0, mc, 0, 0, 0);
      mc = __builtin_amdgcn_mfma_f32_16x16x32_bf16(yah[0], bh0, mc, 0, 0, 0);
      mc = __builtin_amdgcn_mfma_f32_16x16x32_bf16(yal[1], bh1, mc, 0, 0, 0);
      mc = __builtin_amdgcn_mfma_f32_16x16x32_bf16(yah[1], bh1, mc, 0, 0, 0);
    }
    v4f sc;
    {
      const float bs0 = BS[cn];
      sc[0] = bs0; sc[1] = bs0; sc[2] = bs0; sc[3] = bs0;
      const v8s bh0 = *(const v8s_a*)&fw[(16 + nt) * 512 + l * 8];
      const v8s bh1 = *(const v8s_a*)&fw[(20 + nt) * 512 + l * 8];
      sc = __builtin_amdgcn_mfma_f32_16x16x32_bf16(yal[0], bh0, sc, 0, 0, 0);
      sc = __builtin_amdgcn_mfma_f32_16x16x32_bf16(yah[0], bh0, sc, 0, 0, 0);
      sc = __builtin_amdgcn_mfma_f32_16x16x32_bf16(yal[1], bh1, sc, 0, 0, 0);
      sc = __builtin_amdgcn_mfma_f32_16x16x32_bf16(yah[1], bh1, sc, 0, 0, 0);
    }

    float smm = (mc[0] + mc[1]) + (mc[2] + mc[3]);
    smm += __shfl_xor(smm, 16);
    const float mum = smm * 0.125f;
    float sms = (sc[0] + sc[1]) + (sc[2] + sc[3]);
    sms += __shfl_xor(sms, 16);
    const float mus = sms * 0.125f;
    float vm = 0.0f, vs = 0.0f;
#pragma unroll
    for (int q = 0; q < 4; ++q) {
      const float dm = mc[q] - mum; vm = fmaf(dm, dm, vm);
      const float ds = sc[q] - mus; vs = fmaf(ds, ds, vs);
    }
    vm += __shfl_xor(vm, 16);
    vs += __shfl_xor(vs, 16);
    const float sclm = GM[cn] * rsqrtf(vm * 0.125f + 1e-5f);
    const float scls = GS[cn] * rsqrtf(vs * 0.125f + 1e-5f);
    const float bem = BEM[cn];
    const float bes = BES[cn];
    const int oc = obase0 + cn;
#pragma unroll
    for (int q = 0; q < 4; ++q) {
      const float nzq = noise[((g & 1) * 4 + q) * 64 + cn];
      const float lv = (sc[q] - mus) * scls + bes;
      const float ex = exp2f(0.72134752044448f * lv);  // exp(0.5*lv)
      out[oc + q * 64] = (mc[q] - mum) * sclm + bem + ex * nzq;
    }
  }
}

extern "C" void kernel_launch(void* const* d_in, const int* in_sizes, int n_in,
                              void* d_out, int out_size, void* d_ws, size_t ws_size,
                              hipStream_t stream) {
  const float* adj   = (const float*)d_in[0];
  const float* noise = (const float*)d_in[1];
  const float* W1p = (const float*)d_in[2];  const float* b1p = (const float*)d_in[3];
  const float* W2p = (const float*)d_in[4];  const float* b2p = (const float*)d_in[5];
  const float* Wmp = (const float*)d_in[6];  const float* bmp = (const float*)d_in[7];
  const float* gmp = (const float*)d_in[8];  const float* betamp = (const float*)d_in[9];
  const float* Wsp = (const float*)d_in[10]; const float* bsp = (const float*)d_in[11];
  const float* gsp = (const float*)d_in[12]; const float* betasp = (const float*)d_in[13];
  const float* W1n = (const float*)d_in[14]; const float* b1n = (const float*)d_in[15];
  const float* W2n = (const float*)d_in[16]; const float* b2n = (const float*)d_in[17];
  const float* Wmn = (const float*)d_in[18]; const float* bmn = (const float*)d_in[19];
  const float* gmn = (const float*)d_in[20]; const float* betamn = (const float*)d_in[21];
  const float* Wsn = (const float*)d_in[22]; const float* bsn = (const float*)d_in[23];
  const float* gsn = (const float*)d_in[24]; const float* betasn = (const float*)d_in[25];

  short* ws = (short*)d_ws;  // needs 2*28*512*2 = 57344 bytes

  prep_frags<<<2, 256, 0, stream>>>(W1p, W2p, Wmp, Wsp, W1n, W2n, Wmn, Wsn, ws);

  // 64 p-blocks (1024 pairs) + 1984 n-blocks (31744 pairs) = 2048 blocks,
  // 1024 threads = 16 waves per block, one pair per wave, no barriers.
  enc_reg<<<2048, 1024, 0, stream>>>(
      adj, noise, ws,
      b1p, b2p, bmp, gmp, betamp, bsp, gsp, betasp,
      b1n, b2n, bmn, gmn, betamn, bsn, gsn, betasn,
      (float*)d_out);
}

// Round 20
// 79.400 us; speedup vs baseline: 1.2000x; 1.0976x over previous
//
#include <hip/hip_runtime.h>

typedef float v4f __attribute__((ext_vector_type(4)));
typedef short v8s __attribute__((ext_vector_type(8)));
typedef v8s v8s_a __attribute__((may_alias));

#define PBLOCKS 256   // p-path blocks (4 pairs per block, 1024 p-pairs)
#define NEG 0.2f

// Truncation split for ACTIVATIONS/adjacency (validated): hi = bit-truncated
// bf16, lo = trunc(v - hi); v = hi + lo + err, |err| <= 2^-17 |v|.
static __device__ __forceinline__ void split8(const float* e, v8s& hi, v8s& lo) {
  union U { v8s s; unsigned u[4]; } H, L;
#pragma unroll
  for (int j = 0; j < 4; ++j) {
    union { float f; unsigned u; } e0, e1, h0, h1, l0, l1;
    e0.f = e[2 * j]; e1.f = e[2 * j + 1];
    H.u[j] = __builtin_amdgcn_perm(e1.u, e0.u, 0x07060302u);
    h0.u = e0.u & 0xFFFF0000u; h1.u = e1.u & 0xFFFF0000u;
    l0.f = e0.f - h0.f; l1.f = e1.f - h1.f;
    L.u[j] = __builtin_amdgcn_perm(l1.u, l0.u, 0x07060302u);
  }
  hi = H.s; lo = L.s;
}

// Single-plane RNE pack for WEIGHTS (validated round 13).
static __device__ __forceinline__ v8s rne8(const float* e) {
  union U { v8s s; unsigned u[4]; } H;
#pragma unroll
  for (int j = 0; j < 4; ++j) {
    union { float f; unsigned u; } e0, e1;
    e0.f = e[2 * j]; e1.f = e[2 * j + 1];
    const unsigned r0 = e0.u + 0x7FFFu + ((e0.u >> 16) & 1u);
    const unsigned r1 = e1.u + 0x7FFFu + ((e1.u >> 16) & 1u);
    H.u[j] = __builtin_amdgcn_perm(r1, r0, 0x07060302u);
  }
  return H.s;
}

// ---- prep: pack both weight sets' MFMA fragments into d_ws ----
// Layout: ws[set][frag 0..27][lane 0..63][8 bf16]; set 0 = p, 1 = n.
// frags 0..7 = W2, 8..15 = Wm, 16..23 = Ws (B-layout: elem j at
// k = kt*32 + 8g + j, col (nt*16 + n)); 24..27 = W1stk^T (A-layout,
// quarters g>=2 zero).
__global__ __launch_bounds__(256, 1)
void prep_frags(const float* __restrict__ W1p, const float* __restrict__ W2p,
                const float* __restrict__ WMp, const float* __restrict__ WSp,
                const float* __restrict__ W1n, const float* __restrict__ W2n,
                const float* __restrict__ WMn, const float* __restrict__ WSn,
                short* __restrict__ ws)
{
  const bool isp = (blockIdx.x == 0);
  const float* W1 = isp ? W1p : W1n;
  const float* W2 = isp ? W2p : W2n;
  const float* WM = isp ? WMp : WMn;
  const float* WS = isp ? WSp : WSn;
  short* dst = ws + blockIdx.x * 28 * 512;

  const int l = threadIdx.x & 63;
  const int w = threadIdx.x >> 6;
  const int n = l & 15;
  const int g = l >> 4;

  for (int f = w; f < 28; f += 4) {
    float v[8];
    if (f < 24) {
      const float* M = (f < 8) ? W2 : ((f < 16) ? WM : WS);
      const int r = f & 7;
      const int kt = r >> 2;
      const int cn = (r & 3) * 16 + n;
#pragma unroll
      for (int j = 0; j < 8; ++j)
        v[j] = M[(kt * 32 + g * 8 + j) * 64 + cn];
    } else {
      const int ft = f - 24;
#pragma unroll
      for (int j = 0; j < 8; ++j)
        v[j] = (g < 2) ? W1[j * 64 + ft * 16 + n] : 0.0f;
    }
    *(v8s_a*)&dst[f * 512 + l * 8] = rne8(v);
  }
}

// All-register MFMA chain, compensated activations x single-bf16 weights.
// Round 20: restore the validated round-15 kernel (79.5 us PASS). fp16
// single-plane (r18/19) failed structurally (absmax 3.7 — f16 operand
// layout suspect); ILP/TLP expansions (r14/r16/r17) all regressed due to
// register inflation or serialization. One pair per wave is the sweet spot.
//   x1^T = W1stk^T @ Ablk^T   (C lane = pair-row)
//   t    = x1 @ W2            (C lane = feat)     A-frag via CtoA(x1^T)
//   x2^T = t^T @ Ablk^T       (C lane = pair-row)
//   m,s  = x2 @ {Wm,Ws}       (C lane = feat)     A-frag via CtoA(x2^T)
// A/B frag: lane l elem j <-> k = 8*(l>>4)+j (positional, cancels);
// C/D [m89]: row = 4*(l>>4)+reg, col = l&15.
__global__ __launch_bounds__(256, 1)
void enc_reg(const float* __restrict__ adj, const float* __restrict__ noise,
             const short* __restrict__ ws,
             const float* __restrict__ b1p, const float* __restrict__ b2p,
             const float* __restrict__ bmp, const float* __restrict__ gmp,
             const float* __restrict__ betamp,
             const float* __restrict__ bsp, const float* __restrict__ gsp,
             const float* __restrict__ betasp,
             const float* __restrict__ b1n, const float* __restrict__ b2n,
             const float* __restrict__ bmn, const float* __restrict__ gmn,
             const float* __restrict__ betamn,
             const float* __restrict__ bsn, const float* __restrict__ gsn,
             const float* __restrict__ betasn,
             float* __restrict__ out)
{
  const int tid = threadIdx.x;
  const int l = tid & 63;
  const int w = tid >> 6;
  const int n = l & 15;   // preserved axis (pair-row or feat-col)
  const int g = l >> 4;   // lane quarter

  const bool isp = (blockIdx.x < PBLOCKS);
  const int bip = isp ? (int)blockIdx.x : ((int)blockIdx.x - PBLOCKS);

  const float* B1 = isp ? b1p : b1n;   const float* B2 = isp ? b2p : b2n;
  const float* BM = isp ? bmp : bmn;   const float* GM = isp ? gmp : gmn;
  const float* BEM = isp ? betamp : betamn;
  const float* BS = isp ? bsp : bsn;   const float* GS = isp ? gsp : gsn;
  const float* BES = isp ? betasp : betasn;
  const short* fw = ws + (isp ? 0 : 1) * 28 * 512;

  // ---- pair instance indices (one pair per wave) ----
  const int gi = bip * 4 + w;
  int iA, iB;
  if (isp) {
    iA = gi * 64;            // b=2gi,   c=0
    iB = gi * 64 + 32;       // b=2gi+1, c=0
  } else {
    const unsigned n0 = 2u * (unsigned)gi;
    const unsigned n1 = n0 + 1u;
    const unsigned q0 = n0 / 31u;
    const unsigned q1 = n1 / 31u;
    iA = (int)(q0 * 32u + 1u + (n0 - q0 * 31u));
    iB = (int)(q1 * 32u + 1u + (n1 - q1 * 31u));
  }

  // ---- adjacency load + block-diagonal fragment ----
  v8s afh, afl;
  {
    const int instAdj = (n >> 3) ? iB : iA;
    const float4 a0 = *(const float4*)(adj + instAdj * 64 + (n & 7) * 8);
    const float4 a1 = *(const float4*)(adj + instAdj * 64 + (n & 7) * 8 + 4);
    float s = a0.x + a0.y + a0.z + a0.w + a1.x + a1.y + a1.z + a1.w;
    s = (s == 0.0f) ? 1.0f : s;
    const float rinv = (g == (n >> 3)) ? (1.0f / s) : 0.0f;  // 0 kills off-diag
    float e[8];
    e[0] = a0.x * rinv; e[1] = a0.y * rinv; e[2] = a0.z * rinv; e[3] = a0.w * rinv;
    e[4] = a1.x * rinv; e[5] = a1.y * rinv; e[6] = a1.z * rinv; e[7] = a1.w * rinv;
    split8(e, afh, afl);
  }

  // ---- x1^T = W1stk^T @ Ablk^T + b1 (leaky) : C lane = pair-row ----
  v4f x1t[4];
#pragma unroll
  for (int ft = 0; ft < 4; ++ft) {
    const v8s w1h = *(const v8s_a*)&fw[(24 + ft) * 512 + l * 8];
    const float4 b14 = *(const float4*)&B1[ft * 16 + g * 4];
    v4f acc = { b14.x, b14.y, b14.z, b14.w };
    acc = __builtin_amdgcn_mfma_f32_16x16x32_bf16(w1h, afl, acc, 0, 0, 0);
    acc = __builtin_amdgcn_mfma_f32_16x16x32_bf16(w1h, afh, acc, 0, 0, 0);
#pragma unroll
    for (int q = 0; q < 4; ++q) acc[q] = fmaxf(acc[q], NEG * acc[q]);
    x1t[ft] = acc;
  }

  // ---- CtoA(x1t): (lane=pair-row, reg=feat) -> A-frag elems k=feat ----
  v8s xah[2], xal[2];
  {
    const int srcLo = ((g & 1) << 5) + n;
    const int srcHi = srcLo + 16;
#pragma unroll
    for (int kc = 0; kc < 2; ++kc) {
      float e[8];
#pragma unroll
      for (int j = 0; j < 4; ++j) {
        const float lo0 = __shfl(x1t[2 * kc][j], srcLo);
        const float lo1 = __shfl(x1t[2 * kc + 1][j], srcLo);
        const float hi0 = __shfl(x1t[2 * kc][j], srcHi);
        const float hi1 = __shfl(x1t[2 * kc + 1][j], srcHi);
        e[j]     = (g >> 1) ? lo1 : lo0;
        e[j + 4] = (g >> 1) ? hi1 : hi0;
      }
      split8(e, xah[kc], xal[kc]);
    }
  }

  // ---- t = x1 @ W2 : C lane = feat (no bias, no act) ----
  v4f tC[4];
#pragma unroll
  for (int nt = 0; nt < 4; ++nt) {
    v4f acc = { 0.0f, 0.0f, 0.0f, 0.0f };
#pragma unroll
    for (int kc = 0; kc < 2; ++kc) {
      const v8s bh = *(const v8s_a*)&fw[(kc * 4 + nt) * 512 + l * 8];
      acc = __builtin_amdgcn_mfma_f32_16x16x32_bf16(xal[kc], bh, acc, 0, 0, 0);
      acc = __builtin_amdgcn_mfma_f32_16x16x32_bf16(xah[kc], bh, acc, 0, 0, 0);
    }
    tC[nt] = acc;
  }

  // ---- x2^T = t^T @ Ablk^T + b2 (leaky) : C lane = pair-row ----
  v4f x2t[4];
  {
    const int sA = ((g & 1) << 5) + n;
    const int sB = sA + 16;
    const bool bval = (g < 2);
#pragma unroll
    for (int ft = 0; ft < 4; ++ft) {
      float e[8];
#pragma unroll
      for (int j = 0; j < 4; ++j) {
        const float v0 = __shfl(tC[ft][j], sA);
        const float v1 = __shfl(tC[ft][j], sB);
        e[j]     = bval ? v0 : 0.0f;
        e[j + 4] = bval ? v1 : 0.0f;
      }
      v8s th, tl;
      split8(e, th, tl);
      const float4 b24 = *(const float4*)&B2[ft * 16 + g * 4];
      v4f acc = { b24.x, b24.y, b24.z, b24.w };
      acc = __builtin_amdgcn_mfma_f32_16x16x32_bf16(tl, afh, acc, 0, 0, 0);
      acc = __builtin_amdgcn_mfma_f32_16x16x32_bf16(th, afl, acc, 0, 0, 0);
      acc = __builtin_amdgcn_mfma_f32_16x16x32_bf16(th, afh, acc, 0, 0, 0);
#pragma unroll
      for (int q = 0; q < 4; ++q) acc[q] = fmaxf(acc[q], NEG * acc[q]);
      x2t[ft] = acc;
    }
  }

  // ---- CtoA(x2t) -> x2 A-frags ----
  v8s yah[2], yal[2];
  {
    const int srcLo = ((g & 1) << 5) + n;
    const int srcHi = srcLo + 16;
#pragma unroll
    for (int kc = 0; kc < 2; ++kc) {
      float e[8];
#pragma unroll
      for (int j = 0; j < 4; ++j) {
        const float lo0 = __shfl(x2t[2 * kc][j], srcLo);
        const float lo1 = __shfl(x2t[2 * kc + 1][j], srcLo);
        const float hi0 = __shfl(x2t[2 * kc][j], srcHi);
        const float hi1 = __shfl(x2t[2 * kc + 1][j], srcHi);
        e[j]     = (g >> 1) ? lo1 : lo0;
        e[j + 4] = (g >> 1) ? hi1 : hi0;
      }
      split8(e, yah[kc], yal[kc]);
    }
  }

  // ---- m,s = x2 @ {Wm,Ws} + bias ; BN over 8 nodes ; reparam ; store ----
  const int obase0 = ((g >> 1) ? iB : iA) * 512 + (g & 1) * 256;
#pragma unroll
  for (int nt = 0; nt < 4; ++nt) {
    const int cn = nt * 16 + n;
    v4f mc;
    {
      const float bm0 = BM[cn];
      mc[0] = bm0; mc[1] = bm0; mc[2] = bm0; mc[3] = bm0;
      const v8s bh0 = *(const v8s_a*)&fw[(8 + nt) * 512 + l * 8];
      const v8s bh1 = *(const v8s_a*)&fw[(12 + nt) * 512 + l * 8];
      mc = __builtin_amdgcn_mfma_f32_16x16x32_bf16(yal[0], bh0, mc, 0, 0, 0);
      mc = __builtin_amdgcn_mfma_f32_16x16x32_bf16(yah[0], bh0, mc, 0, 0, 0);
      mc = __builtin_amdgcn_mfma_f32_16x16x32_bf16(yal[1], bh1, mc, 0, 0, 0);
      mc = __builtin_amdgcn_mfma_f32_16x16x32_bf16(yah[1], bh1, mc, 0, 0, 0);
    }
    v4f sc;
    {
      const float bs0 = BS[cn];
      sc[0] = bs0; sc[1] = bs0; sc[2] = bs0; sc[3] = bs0;
      const v8s bh0 = *(const v8s_a*)&fw[(16 + nt) * 512 + l * 8];
      const v8s bh1 = *(const v8s_a*)&fw[(20 + nt) * 512 + l * 8];
      sc = __builtin_amdgcn_mfma_f32_16x16x32_bf16(yal[0], bh0, sc, 0, 0, 0);
      sc = __builtin_amdgcn_mfma_f32_16x16x32_bf16(yah[0], bh0, sc, 0, 0, 0);
      sc = __builtin_amdgcn_mfma_f32_16x16x32_bf16(yal[1], bh1, sc, 0, 0, 0);
      sc = __builtin_amdgcn_mfma_f32_16x16x32_bf16(yah[1], bh1, sc, 0, 0, 0);
    }

    float smm = (mc[0] + mc[1]) + (mc[2] + mc[3]);
    smm += __shfl_xor(smm, 16);
    const float mum = smm * 0.125f;
    float sms = (sc[0] + sc[1]) + (sc[2] + sc[3]);
    sms += __shfl_xor(sms, 16);
    const float mus = sms * 0.125f;
    float vm = 0.0f, vs = 0.0f;
#pragma unroll
    for (int q = 0; q < 4; ++q) {
      const float dm = mc[q] - mum; vm = fmaf(dm, dm, vm);
      const float ds = sc[q] - mus; vs = fmaf(ds, ds, vs);
    }
    vm += __shfl_xor(vm, 16);
    vs += __shfl_xor(vs, 16);
    const float sclm = GM[cn] * rsqrtf(vm * 0.125f + 1e-5f);
    const float scls = GS[cn] * rsqrtf(vs * 0.125f + 1e-5f);
    const float bem = BEM[cn];
    const float bes = BES[cn];
    const int oc = obase0 + cn;
#pragma unroll
    for (int q = 0; q < 4; ++q) {
      const float nzq = noise[((g & 1) * 4 + q) * 64 + cn];
      const float lv = (sc[q] - mus) * scls + bes;
      const float ex = exp2f(0.72134752044448f * lv);  // exp(0.5*lv)
      out[oc + q * 64] = (mc[q] - mum) * sclm + bem + ex * nzq;
    }
  }
}

extern "C" void kernel_launch(void* const* d_in, const int* in_sizes, int n_in,
                              void* d_out, int out_size, void* d_ws, size_t ws_size,
                              hipStream_t stream) {
  const float* adj   = (const float*)d_in[0];
  const float* noise = (const float*)d_in[1];
  const float* W1p = (const float*)d_in[2];  const float* b1p = (const float*)d_in[3];
  const float* W2p = (const float*)d_in[4];  const float* b2p = (const float*)d_in[5];
  const float* Wmp = (const float*)d_in[6];  const float* bmp = (const float*)d_in[7];
  const float* gmp = (const float*)d_in[8];  const float* betamp = (const float*)d_in[9];
  const float* Wsp = (const float*)d_in[10]; const float* bsp = (const float*)d_in[11];
  const float* gsp = (const float*)d_in[12]; const float* betasp = (const float*)d_in[13];
  const float* W1n = (const float*)d_in[14]; const float* b1n = (const float*)d_in[15];
  const float* W2n = (const float*)d_in[16]; const float* b2n = (const float*)d_in[17];
  const float* Wmn = (const float*)d_in[18]; const float* bmn = (const float*)d_in[19];
  const float* gmn = (const float*)d_in[20]; const float* betamn = (const float*)d_in[21];
  const float* Wsn = (const float*)d_in[22]; const float* bsn = (const float*)d_in[23];
  const float* gsn = (const float*)d_in[24]; const float* betasn = (const float*)d_in[25];

  short* ws = (short*)d_ws;  // needs 2*28*512*2 = 57344 bytes

  prep_frags<<<2, 256, 0, stream>>>(W1p, W2p, Wmp, Wsp, W1n, W2n, Wmn, Wsn, ws);

  // 256 p-blocks (1024 pairs) + 7936 n-blocks (31744 pairs) = 8192 blocks
  enc_reg<<<8192, 256, 0, stream>>>(
      adj, noise, ws,
      b1p, b2p, bmp, gmp, betamp, bsp, gsp, betasp,
      b1n, b2n, bmn, gmn, betamn, bsn, gsn, betasn,
      (float*)d_out);
}